// Round 1
// baseline (59381.305 us; speedup 1.0000x reference)
//
#include <hip/hip_runtime.h>
#include <stdint.h>
#include <stddef.h>

#define T_STEPS 512
#define B_SZ    128
#define DIN     1024
#define H_SZ    2048
#define NG      8192            // 4*H
#define BH      (B_SZ * H_SZ)   // 262144

typedef __attribute__((ext_vector_type(8))) short bf16x8;
typedef __attribute__((ext_vector_type(4))) float f32x4;

static __device__ __forceinline__ unsigned short f2bf(float x) {
  unsigned int u = __float_as_uint(x);
  u += 0x7fffu + ((u >> 16) & 1u);   // RNE; inputs finite
  return (unsigned short)(u >> 16);
}

static __device__ __forceinline__ float sigm(float x) {
  return 1.0f / (1.0f + __expf(-x));   // safe: e^{+big}=inf -> 0
}
static __device__ __forceinline__ float tanh_(float x) {
  float e = __expf(-2.0f * fabsf(x));  // in (0,1], no overflow
  float t = (1.0f - e) / (1.0f + e);
  return x < 0.0f ? -t : t;
}

// global -> LDS async copy, 16B per lane. LDS dest must be wave-uniform;
// HW writes lane l at ldst + l*16. Global src is per-lane.
static __device__ __forceinline__ void async_load16(const void* gsrc, void* ldst) {
  __builtin_amdgcn_global_load_lds(
      (__attribute__((address_space(1))) void*)(const_cast<void*>(gsrc)),
      (__attribute__((address_space(3))) void*)ldst,
      16, 0, 0);
}

__global__ void cvt_x_bf16(const float4* __restrict__ in, ushort4* __restrict__ out, int n4) {
  int i = blockIdx.x * blockDim.x + threadIdx.x;
  int st = gridDim.x * blockDim.x;
  for (; i < n4; i += st) {
    float4 v = in[i];
    ushort4 o;
    o.x = f2bf(v.x); o.y = f2bf(v.y); o.z = f2bf(v.z); o.w = f2bf(v.w);
    out[i] = o;
  }
}

// out[n][k] (bf16), k<ka from wa[n][k] else wb[n][k-ka]; n = blockIdx.y in [0,8192)
__global__ void build_wcat(const float* __restrict__ wa, const float* __restrict__ wb,
                           unsigned short* __restrict__ outw, int ka, int K) {
  int k = blockIdx.x * blockDim.x + threadIdx.x;
  int n = blockIdx.y;
  if (k >= K) return;
  int kb = K - ka;
  float v = (k < ka) ? wa[(size_t)n * ka + k]
                     : wb[(size_t)n * kb + (k - ka)];
  outw[(size_t)n * K + k] = f2bf(v);
}

__global__ void init_state(const float* __restrict__ h0, const float* __restrict__ c0,
                           unsigned short* __restrict__ hb0, unsigned short* __restrict__ hb1,
                           float* __restrict__ cws) {
  int i = blockIdx.x * blockDim.x + threadIdx.x;
  if (i < BH) {
    hb0[i] = f2bf(h0[i]);        // layer 0 initial h
    hb1[i] = f2bf(h0[BH + i]);   // layer 1 initial h
    cws[i] = c0[i];
    cws[BH + i] = c0[BH + i];
  }
}

// One LSTM cell step, fused GEMM+activation.
// gates[128, 8192] = A[128, K] @ Wcat[8192, K]^T + bias, A = concat(a0 | a1) along K.
// Each WG: 16 h-cols (n0..n0+15) x 4 gate blocks = 128x64 strided output tile, full K.
// 4 waves, wave wv owns row-tiles {wv*16, wv*16+64}. Gate order i,f,g,o (PyTorch).
__global__ __launch_bounds__(256) void lstm_step_fused(
    const unsigned short* __restrict__ a0, int s0, int ksplit,
    const unsigned short* __restrict__ a1,          // row stride H_SZ
    int K,
    const unsigned short* __restrict__ w,           // [NG][K] bf16
    const float* __restrict__ bias,                 // [NG] fp32
    float* __restrict__ c,                          // [B][H] fp32, in-place
    unsigned short* __restrict__ hout,              // [B][H] bf16
    float* __restrict__ fout)                       // optional [B][H] fp32
{
  __shared__ __align__(16) unsigned short Abuf[2][128 * 64];
  __shared__ __align__(16) unsigned short Bbuf[2][64 * 64];

  const int tid  = threadIdx.x;
  const int lane = tid & 63;
  const int wv   = tid >> 6;
  const int n0   = blockIdx.x << 4;

  f32x4 acc[2][4] = {};
  const int KT = K >> 6;

  auto stage = [&](int kt, int bsel) {
    const int kb = kt << 6;
    // A tile: 128 rows x 64 k (16KB) = 1024 x 16B chunks, 4 iters x 4 waves x 64 lanes
#pragma unroll
    for (int it = 0; it < 4; ++it) {
      int cid = it * 256 + wv * 64 + lane;
      int row = cid >> 3;
      int kk  = kb + ((cid & 7) << 3);
      const unsigned short* src =
          (kk < ksplit) ? (a0 + (size_t)row * s0 + kk)
                        : (a1 + (size_t)row * H_SZ + (kk - ksplit));
      async_load16(src, &Abuf[bsel][(it * 256 + wv * 64) * 8]);
    }
    // B tile: 64 gate-rows x 64 k (8KB) = 512 chunks, 2 iters
#pragma unroll
    for (int it = 0; it < 2; ++it) {
      int cid = it * 256 + wv * 64 + lane;
      int nl  = cid >> 3;
      int nn  = ((nl >> 4) << 11) + n0 + (nl & 15);   // gate*2048 + hcol
      const unsigned short* src = w + (size_t)nn * K + kb + ((cid & 7) << 3);
      async_load16(src, &Bbuf[bsel][(it * 256 + wv * 64) * 8]);
    }
  };

  stage(0, 0);
  __syncthreads();   // drains vmcnt(0)

  for (int kt = 0; kt < KT; ++kt) {
    const int cb = kt & 1;
    if (kt + 1 < KT) stage(kt + 1, cb ^ 1);   // issue before compute: overlap
#pragma unroll
    for (int kkk = 0; kkk < 2; ++kkk) {
      const int ko = kkk * 32 + ((lane >> 4) << 3);
      bf16x8 afr[2];
#pragma unroll
      for (int rt = 0; rt < 2; ++rt) {
        int row = wv * 16 + rt * 64 + (lane & 15);
        afr[rt] = *(const bf16x8*)&Abuf[cb][row * 64 + ko];
      }
#pragma unroll
      for (int ct = 0; ct < 4; ++ct) {
        int nl = ct * 16 + (lane & 15);
        bf16x8 bfr = *(const bf16x8*)&Bbuf[cb][nl * 64 + ko];
        acc[0][ct] = __builtin_amdgcn_mfma_f32_16x16x32_bf16(afr[0], bfr, acc[0][ct], 0, 0, 0);
        acc[1][ct] = __builtin_amdgcn_mfma_f32_16x16x32_bf16(afr[1], bfr, acc[1][ct], 0, 0, 0);
      }
    }
    __syncthreads();   // one barrier per k-tile (dbuf: stage wrote cb^1, we read cb)
  }

  // Epilogue: lane holds (i,f,g,o) for (row, hc); C/D map col=lane&15, row=(lane>>4)*4+r
  const int hc  = n0 + (lane & 15);
  const float bi  = bias[hc];
  const float bff = bias[H_SZ + hc];
  const float bg  = bias[2 * H_SZ + hc];
  const float bo  = bias[3 * H_SZ + hc];

#pragma unroll
  for (int rt = 0; rt < 2; ++rt) {
#pragma unroll
    for (int r = 0; r < 4; ++r) {
      int row = wv * 16 + rt * 64 + ((lane >> 4) << 2) + r;
      size_t idx = (size_t)row * H_SZ + hc;
      float iv = sigm(acc[rt][0][r] + bi);
      float fv = sigm(acc[rt][1][r] + bff);
      float gv = tanh_(acc[rt][2][r] + bg);
      float ov = sigm(acc[rt][3][r] + bo);
      float cn = fv * c[idx] + iv * gv;
      c[idx] = cn;
      float hn = ov * tanh_(cn);
      hout[idx] = f2bf(hn);
      if (fout) fout[idx] = hn;
    }
  }
}

extern "C" void kernel_launch(void* const* d_in, const int* in_sizes, int n_in,
                              void* d_out, int out_size, void* d_ws, size_t ws_size,
                              hipStream_t stream) {
  (void)in_sizes; (void)n_in; (void)out_size; (void)ws_size;
  const float* x    = (const float*)d_in[0];
  const float* h0   = (const float*)d_in[1];
  const float* c0   = (const float*)d_in[2];
  const float* Wih0 = (const float*)d_in[3];
  const float* Whh0 = (const float*)d_in[4];
  const float* b0   = (const float*)d_in[5];
  const float* Wih1 = (const float*)d_in[6];
  const float* Whh1 = (const float*)d_in[7];
  const float* b1   = (const float*)d_in[8];
  float* out = (float*)d_out;

  // workspace layout (all 16B aligned): ~244 MB
  unsigned short* xbf = (unsigned short*)d_ws;                     // 512*128*1024 bf16
  unsigned short* Wc0 = xbf + (size_t)T_STEPS * B_SZ * DIN;        // 8192*3072
  unsigned short* Wc1 = Wc0 + (size_t)NG * 3072;                   // 8192*4096
  unsigned short* hb0 = Wc1 + (size_t)NG * 4096;                   // 2 * BH (ping-pong)
  unsigned short* hb1 = hb0 + 2 * (size_t)BH;                      // 2 * BH
  float*          cws = (float*)(hb1 + 2 * (size_t)BH);            // 2 * BH fp32

  cvt_x_bf16<<<dim3(4096), dim3(256), 0, stream>>>(
      (const float4*)x, (ushort4*)xbf, T_STEPS * B_SZ * DIN / 4);
  build_wcat<<<dim3(12, NG), dim3(256), 0, stream>>>(Wih0, Whh0, Wc0, DIN, 3072);
  build_wcat<<<dim3(16, NG), dim3(256), 0, stream>>>(Wih1, Whh1, Wc1, H_SZ, 4096);
  init_state<<<dim3(BH / 256), dim3(256), 0, stream>>>(h0, c0, hb0, hb1, cws);

  for (int t = 0; t < T_STEPS; ++t) {
    const int p = t & 1;
    // layer 0: A = concat(x_t [128x1024] | h0_prev [128x2048]), K=3072
    lstm_step_fused<<<dim3(128), dim3(256), 0, stream>>>(
        xbf + (size_t)t * B_SZ * DIN, DIN, DIN,
        hb0 + (size_t)p * BH,
        3072, Wc0, b0, cws,
        hb0 + (size_t)(p ^ 1) * BH, nullptr);
    // layer 1: A = concat(h0_new | h1_prev), K=4096
    lstm_step_fused<<<dim3(128), dim3(256), 0, stream>>>(
        hb0 + (size_t)(p ^ 1) * BH, H_SZ, H_SZ,
        hb1 + (size_t)p * BH,
        4096, Wc1, b1, cws + BH,
        hb1 + (size_t)(p ^ 1) * BH,
        (t == T_STEPS - 1) ? out : nullptr);
  }
}

// Round 2
// 46723.141 us; speedup vs baseline: 1.2709x; 1.2709x over previous
//
#include <hip/hip_runtime.h>
#include <stdint.h>
#include <stddef.h>

#define T_STEPS 512
#define B_SZ    128
#define DIN     1024
#define H_SZ    2048
#define NG      8192            // 4*H
#define BH      (B_SZ * H_SZ)   // 262144

typedef __attribute__((ext_vector_type(8))) short bf16x8;
typedef __attribute__((ext_vector_type(4))) float f32x4;

static __device__ __forceinline__ unsigned short f2bf(float x) {
  unsigned int u = __float_as_uint(x);
  u += 0x7fffu + ((u >> 16) & 1u);   // RNE; inputs finite
  return (unsigned short)(u >> 16);
}

static __device__ __forceinline__ float sigm(float x) {
  return 1.0f / (1.0f + __expf(-x));
}
static __device__ __forceinline__ float tanh_(float x) {
  float e = __expf(-2.0f * fabsf(x));  // in (0,1], no overflow
  float t = (1.0f - e) / (1.0f + e);
  return x < 0.0f ? -t : t;
}

// global -> LDS async copy, 16B per lane. LDS dest is wave-uniform base;
// HW writes lane l at ldst + l*16. Global src IS per-lane (swizzle there).
static __device__ __forceinline__ void async_load16(const void* gsrc, void* ldst) {
  __builtin_amdgcn_global_load_lds(
      (__attribute__((address_space(1))) void*)(const_cast<void*>(gsrc)),
      (__attribute__((address_space(3))) void*)ldst,
      16, 0, 0);
}

__global__ void cvt_x_bf16(const float4* __restrict__ in, ushort4* __restrict__ out, int n4) {
  int i = blockIdx.x * blockDim.x + threadIdx.x;
  int st = gridDim.x * blockDim.x;
  for (; i < n4; i += st) {
    float4 v = in[i];
    ushort4 o;
    o.x = f2bf(v.x); o.y = f2bf(v.y); o.z = f2bf(v.z); o.w = f2bf(v.w);
    out[i] = o;
  }
}

__global__ void build_wcat(const float* __restrict__ wa, const float* __restrict__ wb,
                           unsigned short* __restrict__ outw, int ka, int K) {
  int k = blockIdx.x * blockDim.x + threadIdx.x;
  int n = blockIdx.y;
  if (k >= K) return;
  int kb = K - ka;
  float v = (k < ka) ? wa[(size_t)n * ka + k]
                     : wb[(size_t)n * kb + (k - ka)];
  outw[(size_t)n * K + k] = f2bf(v);
}

__global__ void init_state(const float* __restrict__ h0, const float* __restrict__ c0,
                           unsigned short* __restrict__ hb0, unsigned short* __restrict__ hb1,
                           float* __restrict__ cws) {
  int i = blockIdx.x * blockDim.x + threadIdx.x;
  if (i < BH) {
    hb0[i] = f2bf(h0[i]);
    hb1[i] = f2bf(h0[BH + i]);
    cws[i] = c0[i];
    cws[BH + i] = c0[BH + i];
  }
}

// gates[128, 8192] = A[128,K] @ Wcat[8192,K]^T + bias; A = concat(a0|a1).
// 256 WGs x 256 thr. WG owns 8 h-cols (32 gate-cols: nl -> gate=nl>>3, hcol=n0+(nl&7)).
// Wave wv owns rows [wv*32, wv*32+32), rt in {0,1} = 16-row subtiles.
// 4-deep LDS ring, 3-ahead prefetch, counted vmcnt (5 loads/wave/stage).
// LDS XOR swizzle: chunk' = chunk ^ (row&7), applied at global-src and ds_read.
__global__ __launch_bounds__(256) void lstm_step_fused(
    const unsigned short* __restrict__ a0, int s0, int ksplit,
    const unsigned short* __restrict__ a1,          // row stride H_SZ
    int K,
    const unsigned short* __restrict__ w,           // [NG][K] bf16
    const float* __restrict__ bias,                 // [NG] fp32
    float* __restrict__ c,                          // [B][H] fp32, in-place
    unsigned short* __restrict__ hout,              // [B][H] bf16
    float* __restrict__ fout)                       // optional [B][H] fp32
{
  __shared__ __align__(16) unsigned short Abuf[4][128 * 64];  // 64 KB
  __shared__ __align__(16) unsigned short Bbuf[4][32 * 64];   // 16 KB

  const int tid  = threadIdx.x;
  const int lane = tid & 63;
  const int wv   = tid >> 6;
  const int n0   = blockIdx.x << 3;   // 8 hcols per WG

  f32x4 acc[2][2] = {};
  const int KT = K >> 6;

  auto stage = [&](int kt, int bsel) {
    const int kb = kt << 6;
    // A tile: 128 rows x 64 k = 16KB = 1024 chunks, 4 per thread
#pragma unroll
    for (int it = 0; it < 4; ++it) {
      int cid = it * 256 + tid;
      int row = cid >> 3;
      int chs = (cid & 7) ^ (row & 7);           // swizzled source chunk
      int kk  = kb + (chs << 3);
      const unsigned short* src =
          (kk < ksplit) ? (a0 + (size_t)row * s0 + kk)
                        : (a1 + (size_t)row * H_SZ + (kk - ksplit));
      async_load16(src, &Abuf[bsel][(it * 256 + wv * 64) * 8]);
    }
    // B tile: 32 gate-rows x 64 k = 4KB = 256 chunks, 1 per thread
    {
      int nl  = tid >> 3;
      int chs = (tid & 7) ^ (nl & 7);
      int nn  = ((nl >> 3) << 11) + n0 + (nl & 7);   // gate*2048 + hcol
      const unsigned short* src = w + (size_t)nn * K + kb + (chs << 3);
      async_load16(src, &Bbuf[bsel][(wv * 64) * 8]);
    }
  };

  // prologue: 3 stages in flight (15 loads/wave); wait oldest 5 -> stage0 ready
  stage(0, 0); stage(1, 1); stage(2, 2);
  asm volatile("s_waitcnt vmcnt(10)" ::: "memory");
  __builtin_amdgcn_s_barrier();
  asm volatile("" ::: "memory");

  for (int kt = 0; kt < KT; ++kt) {
    const int cb = kt & 3;
    if (kt + 3 < KT) stage(kt + 3, (kt + 3) & 3);   // safe: that buf's reads done 2 barriers ago

#pragma unroll
    for (int kkk = 0; kkk < 2; ++kkk) {
      const int ch = kkk * 4 + (lane >> 4);          // logical chunk 0..7
      bf16x8 afr[2], bfr[2];
#pragma unroll
      for (int rt = 0; rt < 2; ++rt) {
        int row = wv * 32 + rt * 16 + (lane & 15);
        afr[rt] = *(const bf16x8*)&Abuf[cb][row * 64 + ((ch ^ (row & 7)) << 3)];
      }
#pragma unroll
      for (int ct = 0; ct < 2; ++ct) {
        int nl = ct * 16 + (lane & 15);
        bfr[ct] = *(const bf16x8*)&Bbuf[cb][nl * 64 + ((ch ^ (nl & 7)) << 3)];
      }
#pragma unroll
      for (int rt = 0; rt < 2; ++rt)
#pragma unroll
        for (int ct = 0; ct < 2; ++ct)
          acc[rt][ct] = __builtin_amdgcn_mfma_f32_16x16x32_bf16(afr[rt], bfr[ct], acc[rt][ct], 0, 0, 0);
    }

    if (kt + 1 < KT) {
      int rem = KT - 1 - kt;   // stages still needed beyond kt
      if (rem >= 3)      asm volatile("s_waitcnt vmcnt(10)" ::: "memory");
      else if (rem == 2) asm volatile("s_waitcnt vmcnt(5)"  ::: "memory");
      else               asm volatile("s_waitcnt vmcnt(0)"  ::: "memory");
      __builtin_amdgcn_s_barrier();
      asm volatile("" ::: "memory");
    }
  }

  // Epilogue. C/D map: col(nl) = lane&15, row = (lane>>4)*4 + r.
  // Lane holds: acc[rt][0] = gate i (lanes&15<8) or f, acc[rt][1] = g or o.
  // shfl_xor(8) pairs complementary gates; low-8 lanes finish rt=0 rows, high-8 rt=1.
  const int hc  = n0 + (lane & 7);
  const float bi  = bias[hc];
  const float bff = bias[H_SZ + hc];
  const float bg  = bias[2 * H_SZ + hc];
  const float bo  = bias[3 * H_SZ + hc];
  const int hi8 = (lane >> 3) & 1;

#pragma unroll
  for (int r = 0; r < 4; ++r) {
    float vA0 = acc[0][0][r], vA1 = acc[0][1][r];
    float vB0 = acc[1][0][r], vB1 = acc[1][1][r];
    float sA0 = __shfl_xor(vA0, 8), sA1 = __shfl_xor(vA1, 8);
    float sB0 = __shfl_xor(vB0, 8), sB1 = __shfl_xor(vB1, 8);
    float gi, gf, gg, go; int rtm;
    if (!hi8) { gi = vA0; gf = sA0; gg = vA1; go = sA1; rtm = 0; }
    else      { gi = sB0; gf = vB0; gg = sB1; go = vB1; rtm = 1; }
    int row = wv * 32 + rtm * 16 + ((lane >> 4) << 2) + r;
    size_t idx = (size_t)row * H_SZ + hc;
    float iv = sigm(gi + bi);
    float fv = sigm(gf + bff);
    float gv = tanh_(gg + bg);
    float ov = sigm(go + bo);
    float cn = fv * c[idx] + iv * gv;
    c[idx] = cn;
    float hn = ov * tanh_(cn);
    hout[idx] = f2bf(hn);
    if (fout) fout[idx] = hn;
  }
}

extern "C" void kernel_launch(void* const* d_in, const int* in_sizes, int n_in,
                              void* d_out, int out_size, void* d_ws, size_t ws_size,
                              hipStream_t stream) {
  (void)in_sizes; (void)n_in; (void)out_size; (void)ws_size;
  const float* x    = (const float*)d_in[0];
  const float* h0   = (const float*)d_in[1];
  const float* c0   = (const float*)d_in[2];
  const float* Wih0 = (const float*)d_in[3];
  const float* Whh0 = (const float*)d_in[4];
  const float* b0   = (const float*)d_in[5];
  const float* Wih1 = (const float*)d_in[6];
  const float* Whh1 = (const float*)d_in[7];
  const float* b1   = (const float*)d_in[8];
  float* out = (float*)d_out;

  unsigned short* xbf = (unsigned short*)d_ws;                     // 512*128*1024 bf16
  unsigned short* Wc0 = xbf + (size_t)T_STEPS * B_SZ * DIN;        // 8192*3072
  unsigned short* Wc1 = Wc0 + (size_t)NG * 3072;                   // 8192*4096
  unsigned short* hb0 = Wc1 + (size_t)NG * 4096;                   // 2 * BH
  unsigned short* hb1 = hb0 + 2 * (size_t)BH;                      // 2 * BH
  float*          cws = (float*)(hb1 + 2 * (size_t)BH);            // 2 * BH fp32

  cvt_x_bf16<<<dim3(4096), dim3(256), 0, stream>>>(
      (const float4*)x, (ushort4*)xbf, T_STEPS * B_SZ * DIN / 4);
  build_wcat<<<dim3(12, NG), dim3(256), 0, stream>>>(Wih0, Whh0, Wc0, DIN, 3072);
  build_wcat<<<dim3(16, NG), dim3(256), 0, stream>>>(Wih1, Whh1, Wc1, H_SZ, 4096);
  init_state<<<dim3(BH / 256), dim3(256), 0, stream>>>(h0, c0, hb0, hb1, cws);

  for (int t = 0; t < T_STEPS; ++t) {
    const int p = t & 1;
    lstm_step_fused<<<dim3(256), dim3(256), 0, stream>>>(
        xbf + (size_t)t * B_SZ * DIN, DIN, DIN,
        hb0 + (size_t)p * BH,
        3072, Wc0, b0, cws,
        hb0 + (size_t)(p ^ 1) * BH, nullptr);
    lstm_step_fused<<<dim3(256), dim3(256), 0, stream>>>(
        hb0 + (size_t)(p ^ 1) * BH, H_SZ, H_SZ,
        hb1 + (size_t)p * BH,
        4096, Wc1, b1, cws + BH,
        hb1 + (size_t)(p ^ 1) * BH,
        (t == T_STEPS - 1) ? out : nullptr);
  }
}